// Round 17
// baseline (431.193 us; speedup 1.0000x reference)
//
#include <hip/hip_runtime.h>
#include <hip/hip_bf16.h>
#include <math.h>

#define HIDDEN 1024
#define NEXP 8
#define TOPK 2
#define INTER 1408
#define SINTER 2816
#define NTOK 4096
#define NROWS (NTOK * TOPK) /* 8192 routed rows */
#define NPANEL 10           /* 8 routed + 2 shared halves */
#define TROWS 16384         /* NROWS + 2*NTOK */
#define MAXT 136            /* (panel, 128-m-block) tasks for gemm_down */
#define MAXT2 72            /* (panel, 256-m-block) tasks for gemm_gu */
#define BPAN (SINTER * HIDDEN) /* interleaved gu B-hat panel elements */

typedef unsigned short ushort_t;
typedef __attribute__((ext_vector_type(8))) short short8;
typedef __attribute__((ext_vector_type(4))) float f32x4;

__device__ __forceinline__ ushort_t f2bf(float f) {
    unsigned int b = __float_as_uint(f);
    unsigned int r = (b + 0x7FFFu + ((b >> 16) & 1u)) >> 16;
    return (ushort_t)r;
}
__device__ __forceinline__ float bf2f(ushort_t u) {
    return __uint_as_float(((unsigned int)u) << 16);
}
__device__ __forceinline__ float silu_f(float g) {
    return g * (1.0f / (1.0f + __expf(-g)));
}
__device__ __forceinline__ int imin(int a, int b) { return a < b ? a : b; }

#define GLDS16(gp, lp) __builtin_amdgcn_global_load_lds(                     \
    (const __attribute__((address_space(1))) void*)(gp),                     \
    (__attribute__((address_space(3))) void*)(lp), 16, 0, 0)

#define SBAR do {                                                            \
        __builtin_amdgcn_sched_barrier(0);                                   \
        __builtin_amdgcn_s_barrier();                                        \
        __builtin_amdgcn_sched_barrier(0);                                   \
    } while (0)

// ================= prep mega-kernel device helpers =================

__device__ __forceinline__ void do_conv_x(const float* __restrict__ src,
                                          ushort_t* __restrict__ dst,
                                          int rem, int tid) {
    int i = (rem * 256 + tid) * 4;
    float4 v = *reinterpret_cast<const float4*>(&src[i]);
    union { ushort_t h[4]; unsigned long long ll; } p;
    p.h[0] = f2bf(v.x); p.h[1] = f2bf(v.y); p.h[2] = f2bf(v.z); p.h[3] = f2bf(v.w);
    *reinterpret_cast<unsigned long long*>(&dst[i]) = p.ll;
}

// fp32 [R][C] -> bf16 [C][R], 64r x 32c tile at (bx, by) of image bz
__device__ __forceinline__ void do_tconv64(const float* __restrict__ src,
                                           ushort_t* __restrict__ dst,
                                           int R, int C, long sstride,
                                           long dstride, int bx, int by,
                                           int bz, int tid) {
    src += (size_t)bz * sstride;
    dst += (size_t)bz * dstride;
    __shared__ float tileA[32][65];
    int ct = bx * 32, rt = by * 64;
    {
        int r = tid >> 2;
        int c0 = (tid & 3) * 8;
        const float* s = &src[(size_t)(rt + r) * C + ct + c0];
        float4 v0 = *reinterpret_cast<const float4*>(s);
        float4 v1 = *reinterpret_cast<const float4*>(s + 4);
        tileA[c0 + 0][r] = v0.x; tileA[c0 + 1][r] = v0.y;
        tileA[c0 + 2][r] = v0.z; tileA[c0 + 3][r] = v0.w;
        tileA[c0 + 4][r] = v1.x; tileA[c0 + 5][r] = v1.y;
        tileA[c0 + 6][r] = v1.z; tileA[c0 + 7][r] = v1.w;
    }
    __syncthreads();
    {
        int c = tid >> 3;
        int r0 = (tid & 7) * 8;
        union { ushort_t h[8]; short8 v; } p;
#pragma unroll
        for (int i = 0; i < 8; i++) p.h[i] = f2bf(tileA[c][r0 + i]);
        *reinterpret_cast<short8*>(&dst[(size_t)(ct + c) * R + rt + r0]) = p.v;
    }
}

// fp32 [HIDDEN][C] -> interleaved bf16 B-hat panels (R15/R16-verified layout)
__device__ __forceinline__ void do_tconv64_gu(const float* __restrict__ src,
                                              ushort_t* __restrict__ dst,
                                              int C, long sstride,
                                              int base_panel, int goff,
                                              int bx, int by, int bz, int tid) {
    src += (size_t)bz * sstride;
    __shared__ float tileB[32][65];
    int ct = bx * 32, rt = by * 64;
    {
        int r = tid >> 2;
        int c0 = (tid & 3) * 8;
        const float* s = &src[(size_t)(rt + r) * C + ct + c0];
        float4 v0 = *reinterpret_cast<const float4*>(s);
        float4 v1 = *reinterpret_cast<const float4*>(s + 4);
        tileB[c0 + 0][r] = v0.x; tileB[c0 + 1][r] = v0.y;
        tileB[c0 + 2][r] = v0.z; tileB[c0 + 3][r] = v0.w;
        tileB[c0 + 4][r] = v1.x; tileB[c0 + 5][r] = v1.y;
        tileB[c0 + 6][r] = v1.z; tileB[c0 + 7][r] = v1.w;
    }
    __syncthreads();
    {
        int c = tid >> 3;
        int r0 = (tid & 7) * 8;
        int gc = ct + c;
        int panel = base_panel + bz + gc / INTER;
        int rl = gc % INTER;
        int Rrow = ((rl >> 5) << 6) + (rl & 31) + goff;
        union { ushort_t h[8]; short8 v; } p;
#pragma unroll
        for (int i = 0; i < 8; i++) p.h[i] = f2bf(tileB[c][r0 + i]);
        *reinterpret_cast<short8*>(
            &dst[(size_t)panel * BPAN + (size_t)Rrow * HIDDEN + rt + r0]) = p.v;
    }
}

// gate + assign for one token (one 64-lane wave)
__device__ __forceinline__ void do_gate(const float* __restrict__ x,
                                        const float* __restrict__ gw,
                                        int* __restrict__ top_i,
                                        float* __restrict__ top_w,
                                        int* __restrict__ cnt,
                                        int* __restrict__ rnk,
                                        int t, int lane) {
    const float* xr = x + (size_t)t * HIDDEN;
    float acc[NEXP];
#pragma unroll
    for (int e = 0; e < NEXP; e++) acc[e] = 0.f;
    for (int j = 0; j < HIDDEN / 64; j++) {
        float xv = xr[lane + 64 * j];
#pragma unroll
        for (int e = 0; e < NEXP; e++)
            acc[e] = fmaf(xv, gw[e * HIDDEN + lane + 64 * j], acc[e]);
    }
#pragma unroll
    for (int e = 0; e < NEXP; e++) {
        float v = acc[e];
        for (int off = 32; off > 0; off >>= 1) v += __shfl_xor(v, off, 64);
        acc[e] = v;
    }
    if (lane == 0) {
        float mx = acc[0];
        for (int e = 1; e < NEXP; e++) mx = fmaxf(mx, acc[e]);
        float s[NEXP];
        float sum = 0.f;
        for (int e = 0; e < NEXP; e++) { s[e] = __expf(acc[e] - mx); sum += s[e]; }
        float inv = 1.0f / sum;
        for (int e = 0; e < NEXP; e++) s[e] *= inv;
        int e0 = 0;
        for (int e = 1; e < NEXP; e++) if (s[e] > s[e0]) e0 = e;
        int e1 = -1;
        for (int e = 0; e < NEXP; e++) {
            if (e == e0) continue;
            if (e1 < 0 || s[e] > s[e1]) e1 = e;
        }
        float w0 = s[e0], w1 = s[e1];
        float denom = w0 + w1 + 1e-20f;
        top_i[t * 2 + 0] = e0;
        top_i[t * 2 + 1] = e1;
        top_w[t * 2 + 0] = w0 / denom;
        top_w[t * 2 + 1] = w1 / denom;
        rnk[t * 2 + 0] = atomicAdd(&cnt[e0], 1);
        rnk[t * 2 + 1] = atomicAdd(&cnt[e1], 1);
    }
}

// ============ prep: conversions + gate/assign, one launch ==================
// block ranges: [0,4096) conv_x | [..+5632) wg | [..+5632) wu | [..+1408) swg
// | [..+1408) swu | [..+5632) wd | [..+1408) swd | [..+1024) gate (4 tok/blk)
#define PB_CONVX 4096
#define PB_WGU   5632  /* 44 x 16 x 8 */
#define PB_SW    1408  /* 88 x 16 */
#define PB_WD    5632  /* 32 x 22 x 8 */
#define PB_SWD   1408  /* 32 x 22 x 2 */
#define PB_GATE  1024
#define PB_TOTAL (PB_CONVX + 2 * PB_WGU + 2 * PB_SW + PB_WD + PB_SWD + PB_GATE)

__global__ __launch_bounds__(256) void prep_kernel(
    const float* __restrict__ x, const float* __restrict__ gw,
    const float* __restrict__ wg, const float* __restrict__ wu,
    const float* __restrict__ wd, const float* __restrict__ swg,
    const float* __restrict__ swu, const float* __restrict__ swd,
    ushort_t* __restrict__ xb, ushort_t* __restrict__ bhat,
    ushort_t* __restrict__ wdT, int* __restrict__ top_i,
    float* __restrict__ top_w, int* __restrict__ cnt, int* __restrict__ rnk) {
    int bid = blockIdx.x;
    int tid = threadIdx.x;
    if (bid < PB_CONVX) {
        do_conv_x(x, xb, bid, tid);
        return;
    }
    bid -= PB_CONVX;
    if (bid < PB_WGU) {  // wg -> bhat, goff 0
        int bx = bid % 44, by = (bid / 44) % 16, bz = bid / (44 * 16);
        do_tconv64_gu(wg, bhat, INTER, (long)HIDDEN * INTER, 0, 0, bx, by, bz, tid);
        return;
    }
    bid -= PB_WGU;
    if (bid < PB_WGU) {  // wu -> bhat, goff 32
        int bx = bid % 44, by = (bid / 44) % 16, bz = bid / (44 * 16);
        do_tconv64_gu(wu, bhat, INTER, (long)HIDDEN * INTER, 0, 32, bx, by, bz, tid);
        return;
    }
    bid -= PB_WGU;
    if (bid < PB_SW) {  // swg -> bhat panels 8,9, goff 0
        int bx = bid % 88, by = bid / 88;
        do_tconv64_gu(swg, bhat, SINTER, 0, 8, 0, bx, by, 0, tid);
        return;
    }
    bid -= PB_SW;
    if (bid < PB_SW) {  // swu
        int bx = bid % 88, by = bid / 88;
        do_tconv64_gu(swu, bhat, SINTER, 0, 8, 32, bx, by, 0, tid);
        return;
    }
    bid -= PB_SW;
    if (bid < PB_WD) {  // wd -> wdT
        int bx = bid % 32, by = (bid / 32) % 22, bz = bid / (32 * 22);
        do_tconv64(wd, wdT, INTER, HIDDEN, (long)INTER * HIDDEN,
                   (long)HIDDEN * INTER, bx, by, bz, tid);
        return;
    }
    bid -= PB_WD;
    if (bid < PB_SWD) {  // swd -> wdT panels 8,9
        int bx = bid % 32, by = (bid / 32) % 22, bz = bid / (32 * 22);
        do_tconv64(swd, wdT + (size_t)8 * HIDDEN * INTER, INTER, HIDDEN,
                   (long)INTER * HIDDEN, (long)HIDDEN * INTER, bx, by, bz, tid);
        return;
    }
    bid -= PB_SWD;
    {  // gate: 4 tokens per block, one per wave
        int t = bid * 4 + (tid >> 6);
        do_gate(x, gw, top_i, top_w, cnt, rnk, t, tid & 63);
    }
}

// ============ scanfill: offs + fill + task tables, one launch ==============
__global__ __launch_bounds__(256) void scanfill_kernel(
    const int* __restrict__ cnt, const int* __restrict__ top_i,
    const float* __restrict__ top_w, const int* __restrict__ rnk,
    int* __restrict__ offs2, int* __restrict__ cnt2, int* __restrict__ task_pm,
    int* __restrict__ task256, int* __restrict__ tok_of_row,
    float* __restrict__ w_of_row, int* __restrict__ inv_row) {
    int offs[NEXP];
    int o = 0;
#pragma unroll
    for (int e = 0; e < NEXP; e++) { offs[e] = o; o += cnt[e]; }
    int j = blockIdx.x * 256 + threadIdx.x;  // 0..8191
    int e = top_i[j];
    int row = offs[e] + rnk[j];
    tok_of_row[row] = j;  // token = j>>1
    w_of_row[row] = top_w[j];
    inv_row[j] = row;
    tok_of_row[NROWS + j] = (j & (NTOK - 1)) << 1;  // shared rows
    if (blockIdx.x == 0 && threadIdx.x == 0) {
        int c2[NPANEL];
        for (int k = 0; k < NEXP; k++) { offs2[k] = offs[k]; c2[k] = cnt[k]; }
        offs2[8] = NROWS;          c2[8] = NTOK;
        offs2[9] = NROWS + NTOK;   c2[9] = NTOK;
        offs2[10] = TROWS;
        for (int k = 0; k < NPANEL; k++) cnt2[k] = c2[k];
        int t = 0;
        for (int k = 0; k < NPANEL; k++)
            for (int m0 = 0; m0 < c2[k]; m0 += 128)
                task_pm[t++] = (k << 16) | (m0 >> 7);
        for (; t < MAXT; t++) task_pm[t] = -1;
        int u = 0;
        for (int k = 0; k < NPANEL; k++)
            for (int m0 = 0; m0 < c2[k]; m0 += 256)
                task256[u++] = (k << 16) | (m0 >> 8);
        for (; u < MAXT2; u++) task256[u] = -1;
    }
}

// ============ GEMM 1: act = silu(x@Wg)*(x@Wu)  (R16-measured, unchanged) ===
__global__ __launch_bounds__(512, 1) void gemm_gu(
    const ushort_t* __restrict__ xb, const ushort_t* __restrict__ Bhat,
    ushort_t* __restrict__ act, const int* __restrict__ tok_of_row,
    const int* __restrict__ offs2, const int* __restrict__ cnt2,
    const int* __restrict__ task256) {
    int T = gridDim.x;  // MAXT2 * (SINTER/256) = 792, %8==0
    int orig = blockIdx.x;
    int logical = (orig & 7) * (T >> 3) + (orig >> 3);
    int task = logical % MAXT2;
    int nidx = logical / MAXT2;
    int tk = task256[task];
    if (tk < 0) return;
    int e = tk >> 16;
    int m0 = (tk & 0xffff) << 8;
    int mcnt = cnt2[e];
    int base = offs2[e];
    int n0h = nidx * 256;
    const ushort_t* B = Bhat + (size_t)e * BPAN;

    __shared__ short As[2][2][16][512];
    __shared__ short Bs[2][2][16][512];

    int tid = threadIdx.x;
    int wave = tid >> 6, lane = tid & 63;
    int wm = wave >> 2, wn = wave & 3;
    int lr = lane & 15;
    int kq = (lane >> 4) * 8;

    int ar0 = 16 * (2 * wave) + lr, ar1 = ar0 + 16;
    int rr0 = base + imin(m0 + ar0, mcnt - 1);
    int rr1 = base + imin(m0 + ar1, mcnt - 1);
    const ushort_t* srcA0 = xb + (size_t)(tok_of_row[rr0] >> 1) * HIDDEN + kq;
    const ushort_t* srcA1 = xb + (size_t)(tok_of_row[rr1] >> 1) * HIDDEN + kq;
    const ushort_t* srcB0 = B + (size_t)(n0h + 16 * (2 * wave) + lr) * HIDDEN + kq;
    const ushort_t* srcB1 = srcB0 + (size_t)16 * HIDDEN;

    f32x4 acc[8][4] = {};

#define SGA(d, s, kk) do {                                                   \
        GLDS16(srcA0 + (kk) + (s) * 32, &As[d][s][2 * wave][0]);             \
        GLDS16(srcA1 + (kk) + (s) * 32, &As[d][s][2 * wave + 1][0]);         \
    } while (0)
#define SGB(d, s, kk) do {                                                   \
        GLDS16(srcB0 + (kk) + (s) * 32, &Bs[d][s][2 * wave][0]);             \
        GLDS16(srcB1 + (kk) + (s) * 32, &Bs[d][s][2 * wave + 1][0]);         \
    } while (0)

    SGA(0, 0, 0); SGB(0, 0, 0); SGA(0, 1, 0); SGB(0, 1, 0);
    SGA(1, 0, 64); SGB(1, 0, 64); SGA(1, 1, 64); SGB(1, 1, 64);

    const int NT = HIDDEN / 64;  // 16
    short8 a[8], b0, b1, b2, b3;
    for (int t = 0; t < NT; t++) {
        int d = t & 1;
        int kk1 = (t + 1) * 64, kk2 = (t + 2) * 64;
        bool st1 = (t >= 1) && (t + 1 < NT);
        bool st2 = (t + 2 < NT);
        if (t == 0)           asm volatile("s_waitcnt vmcnt(8)" ::: "memory");
        else if (t == NT - 1) asm volatile("s_waitcnt vmcnt(0)" ::: "memory");
        else                  asm volatile("s_waitcnt vmcnt(4)" ::: "memory");
        SBAR;
#pragma unroll
        for (int m = 0; m < 8; m++)
            a[m] = *reinterpret_cast<const short8*>(&As[d][0][wm * 8 + m][lane * 8]);
        b0 = *reinterpret_cast<const short8*>(&Bs[d][0][wn * 4 + 0][lane * 8]);
        b1 = *reinterpret_cast<const short8*>(&Bs[d][0][wn * 4 + 1][lane * 8]);
        if (st1) SGA(d ^ 1, 1, kk1);
        __builtin_amdgcn_s_setprio(1);
#pragma unroll
        for (int m = 0; m < 8; m++) {
            acc[m][0] = __builtin_amdgcn_mfma_f32_16x16x32_bf16(a[m], b0, acc[m][0], 0, 0, 0);
            acc[m][1] = __builtin_amdgcn_mfma_f32_16x16x32_bf16(a[m], b1, acc[m][1], 0, 0, 0);
        }
        __builtin_amdgcn_s_setprio(0);
        SBAR;
        b2 = *reinterpret_cast<const short8*>(&Bs[d][0][wn * 4 + 2][lane * 8]);
        b3 = *reinterpret_cast<const short8*>(&Bs[d][0][wn * 4 + 3][lane * 8]);
        if (st1) SGB(d ^ 1, 1, kk1);
        __builtin_amdgcn_s_setprio(1);
#pragma unroll
        for (int m = 0; m < 8; m++) {
            acc[m][2] = __builtin_amdgcn_mfma_f32_16x16x32_bf16(a[m], b2, acc[m][2], 0, 0, 0);
            acc[m][3] = __builtin_amdgcn_mfma_f32_16x16x32_bf16(a[m], b3, acc[m][3], 0, 0, 0);
        }
        __builtin_amdgcn_s_setprio(0);
        SBAR;
#pragma unroll
        for (int m = 0; m < 8; m++)
            a[m] = *reinterpret_cast<const short8*>(&As[d][1][wm * 8 + m][lane * 8]);
        b0 = *reinterpret_cast<const short8*>(&Bs[d][1][wn * 4 + 0][lane * 8]);
        b1 = *reinterpret_cast<const short8*>(&Bs[d][1][wn * 4 + 1][lane * 8]);
        if (st2) SGA(d, 0, kk2);
        __builtin_amdgcn_s_setprio(1);
#pragma unroll
        for (int m = 0; m < 8; m++) {
            acc[m][0] = __builtin_amdgcn_mfma_f32_16x16x32_bf16(a[m], b0, acc[m][0], 0, 0, 0);
            acc[m][1] = __builtin_amdgcn_mfma_f32_16x16x32_bf16(a[m], b1, acc[m][1], 0, 0, 0);
        }
        __builtin_amdgcn_s_setprio(0);
        SBAR;
        b2 = *reinterpret_cast<const short8*>(&Bs[d][1][wn * 4 + 2][lane * 8]);
        b3 = *reinterpret_cast<const short8*>(&Bs[d][1][wn * 4 + 3][lane * 8]);
        if (st2) SGB(d, 0, kk2);
        __builtin_amdgcn_s_setprio(1);
#pragma unroll
        for (int m = 0; m < 8; m++) {
            acc[m][2] = __builtin_amdgcn_mfma_f32_16x16x32_bf16(a[m], b2, acc[m][2], 0, 0, 0);
            acc[m][3] = __builtin_amdgcn_mfma_f32_16x16x32_bf16(a[m], b3, acc[m][3], 0, 0, 0);
        }
        __builtin_amdgcn_s_setprio(0);
    }
#undef SGA
#undef SGB

    int colbase = 32 * (nidx * 4 + wn);
#pragma unroll
    for (int m = 0; m < 8; m++) {
#pragma unroll
        for (int r = 0; r < 4; r++) {
            int gm = m0 + wm * 128 + m * 16 + (lane >> 4) * 4 + r;
            if (gm < mcnt) {
#pragma unroll
                for (int n = 0; n < 2; n++) {
                    float g = acc[m][n][r], u = acc[m][n + 2][r];
                    act[(size_t)(base + gm) * INTER + colbase + n * 16 + lr] =
                        f2bf(silu_f(g) * u);
                }
            }
        }
    }
}

// ============ GEMM 2: part = act @ Wd (R11-proven config, unchanged) =======
__global__ __launch_bounds__(256, 2) void gemm_down(
    const ushort_t* __restrict__ act, const ushort_t* __restrict__ WdT,
    ushort_t* __restrict__ part, const int* __restrict__ offs2,
    const int* __restrict__ cnt2, const int* __restrict__ task_pm) {
    int T = gridDim.x;
    int orig = blockIdx.x;
    int logical = (orig & 7) * (T >> 3) + (orig >> 3);
    int task = logical % MAXT;
    int nidx = logical / MAXT;
    int tk = task_pm[task];
    if (tk < 0) return;
    int e = tk >> 16;
    int m0 = (tk & 0xffff) << 7;
    int mcnt = cnt2[e];
    int base = offs2[e];
    int n0 = nidx * 256;
    const ushort_t* Bd = WdT + (size_t)e * HIDDEN * INTER;

    __shared__ short As[8 * 1024];
    __shared__ short Bs[16 * 1024];

    int tid = threadIdx.x;
    int wave = tid >> 6, lane = tid & 63;
    int wr = wave >> 1, wc = wave & 1;
    int lr = lane & 15;
    int kq = (lane >> 4) * 8;

    const ushort_t* srcA0 = act + (size_t)(base + m0 + 32 * wave + lr) * INTER + kq;
    const ushort_t* srcA1 = srcA0 + (size_t)16 * INTER;
    const ushort_t* srcB0 = Bd + (size_t)(n0 + 64 * wave + lr) * INTER + kq;
    const ushort_t* srcB1 = srcB0 + (size_t)16 * INTER;
    const ushort_t* srcB2 = srcB0 + (size_t)32 * INTER;
    const ushort_t* srcB3 = srcB0 + (size_t)48 * INTER;

    f32x4 acc[4][8] = {};

    for (int k0 = 0; k0 < INTER; k0 += 64) {
        GLDS16(srcA0 + k0,      &As[(2 * wave) * 1024]);
        GLDS16(srcA0 + k0 + 32, &As[(2 * wave) * 1024 + 512]);
        GLDS16(srcA1 + k0,      &As[(2 * wave + 1) * 1024]);
        GLDS16(srcA1 + k0 + 32, &As[(2 * wave + 1) * 1024 + 512]);
        GLDS16(srcB0 + k0,      &Bs[(4 * wave) * 1024]);
        GLDS16(srcB0 + k0 + 32, &Bs[(4 * wave) * 1024 + 512]);
        GLDS16(srcB1 + k0,      &Bs[(4 * wave + 1) * 1024]);
        GLDS16(srcB1 + k0 + 32, &Bs[(4 * wave + 1) * 1024 + 512]);
        GLDS16(srcB2 + k0,      &Bs[(4 * wave + 2) * 1024]);
        GLDS16(srcB2 + k0 + 32, &Bs[(4 * wave + 2) * 1024 + 512]);
        GLDS16(srcB3 + k0,      &Bs[(4 * wave + 3) * 1024]);
        GLDS16(srcB3 + k0 + 32, &Bs[(4 * wave + 3) * 1024 + 512]);
        __syncthreads();
#pragma unroll
        for (int s = 0; s < 2; s++) {
            short8 a[4], b[8];
#pragma unroll
            for (int mi = 0; mi < 4; mi++)
                a[mi] = *reinterpret_cast<const short8*>(
                    &As[(wr * 4 + mi) * 1024 + s * 512 + lane * 8]);
#pragma unroll
            for (int ni = 0; ni < 8; ni++)
                b[ni] = *reinterpret_cast<const short8*>(
                    &Bs[(wc * 8 + ni) * 1024 + s * 512 + lane * 8]);
#pragma unroll
            for (int mi = 0; mi < 4; mi++)
#pragma unroll
                for (int ni = 0; ni < 8; ni++)
                    acc[mi][ni] = __builtin_amdgcn_mfma_f32_16x16x32_bf16(
                        a[mi], b[ni], acc[mi][ni], 0, 0, 0);
        }
        __syncthreads();
    }

#pragma unroll
    for (int mi = 0; mi < 4; mi++) {
#pragma unroll
        for (int r = 0; r < 4; r++) {
            int gm = m0 + wr * 64 + mi * 16 + (lane >> 4) * 4 + r;
            if (gm < mcnt) {
#pragma unroll
                for (int ni = 0; ni < 8; ni++) {
                    int col = n0 + wc * 128 + ni * 16 + lr;
                    part[(size_t)(base + gm) * HIDDEN + col] = f2bf(acc[mi][ni][r]);
                }
            }
        }
    }
}

// ============ combine: out[t] = w0*part[r0] + w1*part[r1] + part[s8] + part[s9]
__global__ __launch_bounds__(256) void combine_kernel(
    const ushort_t* __restrict__ part, const int* __restrict__ inv_row,
    const float* __restrict__ w_of_row, float* __restrict__ out) {
    int t = blockIdx.x;
    int c = threadIdx.x * 4;
    int r0 = inv_row[2 * t], r1 = inv_row[2 * t + 1];
    float w0 = w_of_row[r0], w1 = w_of_row[r1];
    ushort4 a0 = *reinterpret_cast<const ushort4*>(&part[(size_t)r0 * HIDDEN + c]);
    ushort4 a1 = *reinterpret_cast<const ushort4*>(&part[(size_t)r1 * HIDDEN + c]);
    ushort4 a2 = *reinterpret_cast<const ushort4*>(&part[((size_t)NROWS + t) * HIDDEN + c]);
    ushort4 a3 = *reinterpret_cast<const ushort4*>(&part[((size_t)NROWS + NTOK + t) * HIDDEN + c]);
    float4 o;
    o.x = w0 * bf2f(a0.x) + w1 * bf2f(a1.x) + bf2f(a2.x) + bf2f(a3.x);
    o.y = w0 * bf2f(a0.y) + w1 * bf2f(a1.y) + bf2f(a2.y) + bf2f(a3.y);
    o.z = w0 * bf2f(a0.z) + w1 * bf2f(a1.z) + bf2f(a2.z) + bf2f(a3.z);
    o.w = w0 * bf2f(a0.w) + w1 * bf2f(a1.w) + bf2f(a2.w) + bf2f(a3.w);
    *reinterpret_cast<float4*>(&out[(size_t)t * HIDDEN + c]) = o;
}

extern "C" void kernel_launch(void* const* d_in, const int* in_sizes, int n_in,
                              void* d_out, int out_size, void* d_ws, size_t ws_size,
                              hipStream_t stream) {
    const float* x   = (const float*)d_in[0];
    const float* gw  = (const float*)d_in[1];
    const float* wg  = (const float*)d_in[2];
    const float* wu  = (const float*)d_in[3];
    const float* wd  = (const float*)d_in[4];
    const float* swg = (const float*)d_in[5];
    const float* swu = (const float*)d_in[6];
    const float* swd = (const float*)d_in[7];
    float* out = (float*)d_out;

    // ---- workspace layout ----
    const size_t XB   = (size_t)NTOK * HIDDEN;
    const size_t BHAT = (size_t)NPANEL * BPAN;
    const size_t WDT  = (size_t)NPANEL * INTER * HIDDEN;
    const size_t ACT  = (size_t)TROWS * INTER;
    const size_t PART = (size_t)TROWS * HIDDEN;
    ushort_t* xb   = (ushort_t*)d_ws;
    ushort_t* bhat = xb + XB;
    ushort_t* wdT  = bhat + BHAT;
    ushort_t* act  = wdT + WDT;
    ushort_t* part = act + ACT;
    int* ib = (int*)(part + PART);
    int* top_i      = ib;                 // NROWS
    int* rnk        = ib + NROWS;         // NROWS
    int* cnt        = ib + 2 * NROWS;     // 8
    int* offs2      = ib + 2 * NROWS + 8; // 16
    int* cnt2       = offs2 + 16;         // 16
    int* task_pm    = cnt2 + 16;          // MAXT
    int* task256    = task_pm + MAXT;     // MAXT2
    int* tok_of_row = task256 + MAXT2;    // TROWS
    int* inv_row    = tok_of_row + TROWS; // NROWS
    float* top_w    = (float*)(inv_row + NROWS);  // NROWS
    float* w_of_row = top_w + NROWS;              // TROWS

    // ---- 1. prep: all conversions + gate/assign in ONE launch ----
    hipMemsetAsync(cnt, 0, 8 * sizeof(int), stream);
    prep_kernel<<<PB_TOTAL, 256, 0, stream>>>(x, gw, wg, wu, wd, swg, swu, swd,
                                              xb, bhat, wdT, top_i, top_w,
                                              cnt, rnk);

    // ---- 2. scan + fill + task tables in ONE launch ----
    scanfill_kernel<<<NROWS / 256, 256, 0, stream>>>(
        cnt, top_i, top_w, rnk, offs2, cnt2, task_pm, task256, tok_of_row,
        w_of_row, inv_row);

    // ---- 3. grouped SwiGLU GEMMs + combine ----
    gemm_gu<<<MAXT2 * (SINTER / 256), 512, 0, stream>>>(
        xb, bhat, act, tok_of_row, offs2, cnt2, task256);
    gemm_down<<<MAXT * (HIDDEN / 256), 256, 0, stream>>>(
        act, wdT, part, offs2, cnt2, task_pm);
    combine_kernel<<<NTOK, 256, 0, stream>>>(part, inv_row, w_of_row, out);
}

// Round 18
// 395.253 us; speedup vs baseline: 1.0909x; 1.0909x over previous
//
#include <hip/hip_runtime.h>
#include <hip/hip_bf16.h>
#include <math.h>

#define HIDDEN 1024
#define NEXP 8
#define TOPK 2
#define INTER 1408
#define SINTER 2816
#define NTOK 4096
#define NROWS (NTOK * TOPK) /* 8192 routed rows */
#define NPANEL 10           /* 8 routed + 2 shared halves */
#define TROWS 16384         /* NROWS + 2*NTOK */
#define MAXT 136            /* max (panel, m-block) tasks */

typedef unsigned short ushort_t;
typedef __attribute__((ext_vector_type(8))) short short8;
typedef __attribute__((ext_vector_type(4))) float f32x4;

__device__ __forceinline__ ushort_t f2bf(float f) {
    unsigned int b = __float_as_uint(f);
    unsigned int r = (b + 0x7FFFu + ((b >> 16) & 1u)) >> 16;
    return (ushort_t)r;
}
__device__ __forceinline__ float bf2f(ushort_t u) {
    return __uint_as_float(((unsigned int)u) << 16);
}
__device__ __forceinline__ float silu_f(float g) {
    return g * (1.0f / (1.0f + __expf(-g)));
}
__device__ __forceinline__ int imin(int a, int b) { return a < b ? a : b; }

#define GLDS16(gp, lp) __builtin_amdgcn_global_load_lds(                     \
    (const __attribute__((address_space(1))) void*)(gp),                     \
    (__attribute__((address_space(3))) void*)(lp), 16, 0, 0)

// ---------------- fp32 -> bf16 elementwise (x) ----------------
__global__ void conv_x(const float* __restrict__ src, ushort_t* __restrict__ dst) {
    int i = (blockIdx.x * 256 + threadIdx.x) * 4;
    float4 v = *reinterpret_cast<const float4*>(&src[i]);
    union { ushort_t h[4]; unsigned long long ll; } p;
    p.h[0] = f2bf(v.x); p.h[1] = f2bf(v.y); p.h[2] = f2bf(v.z); p.h[3] = f2bf(v.w);
    *reinterpret_cast<unsigned long long*>(&dst[i]) = p.ll;
}

// ---- fp32 [R][C] -> bf16 [C][R] transpose-convert, WIDE tiles -------------
// Tile: RT src-rows x 32 src-cols (RT = 512 or 704).  bf16 LDS tile stride
// 708 shorts: paired-row dword LDS writes land 2-way (free); dst rows are
// written as RT*2 bytes CONTIGUOUS (1-1.4KB per DRAM page vs 128B before).
__global__ __launch_bounds__(256) void tconv_wide(
    const float* __restrict__ src, ushort_t* __restrict__ dst,
    int R, int C, long sstride, long dstride, int RT) {
    src += (size_t)blockIdx.z * sstride;
    dst += (size_t)blockIdx.z * dstride;
    __shared__ short tile[32 * 708];  // 45.3 KB
    int ct = blockIdx.x * 32, rt = blockIdx.y * RT;
    int t = threadIdx.x;
    int nri = RT >> 6;  // iters (8 or 11)
    for (int it = 0; it < nri; it++) {
        int r = it * 64 + 2 * (t >> 3);  // even row in [0, RT)
        int c0 = (t & 7) * 4;
        const float* s0 = &src[(size_t)(rt + r) * C + ct + c0];
        float4 v0 = *reinterpret_cast<const float4*>(s0);
        float4 v1 = *reinterpret_cast<const float4*>(s0 + C);
        unsigned int d0 = (unsigned)f2bf(v0.x) | ((unsigned)f2bf(v1.x) << 16);
        unsigned int d1 = (unsigned)f2bf(v0.y) | ((unsigned)f2bf(v1.y) << 16);
        unsigned int d2 = (unsigned)f2bf(v0.z) | ((unsigned)f2bf(v1.z) << 16);
        unsigned int d3 = (unsigned)f2bf(v0.w) | ((unsigned)f2bf(v1.w) << 16);
        *reinterpret_cast<unsigned int*>(&tile[(c0 + 0) * 708 + r]) = d0;
        *reinterpret_cast<unsigned int*>(&tile[(c0 + 1) * 708 + r]) = d1;
        *reinterpret_cast<unsigned int*>(&tile[(c0 + 2) * 708 + r]) = d2;
        *reinterpret_cast<unsigned int*>(&tile[(c0 + 3) * 708 + r]) = d3;
    }
    __syncthreads();
    int cpr = RT >> 3;  // 16B chunks per dst row (64 or 88)
    for (int it = 0; it < nri; it++) {
        int q = it * 256 + t;
        int cc = q / cpr;
        int off = (q - cc * cpr) * 8;
        unsigned long long lo =
            *reinterpret_cast<const unsigned long long*>(&tile[cc * 708 + off]);
        unsigned long long hi =
            *reinterpret_cast<const unsigned long long*>(&tile[cc * 708 + off + 4]);
        ulonglong2 val;
        val.x = lo; val.y = hi;
        *reinterpret_cast<ulonglong2*>(&dst[(size_t)(ct + cc) * R + rt + off]) = val;
    }
}

// ---------------- gate: logits -> softmax -> top2 -> normalized weights ----
__global__ void gate_kernel(const float* __restrict__ x, const float* __restrict__ gw,
                            int* __restrict__ top_i, float* __restrict__ top_w) {
    int t = blockIdx.x;
    int lane = threadIdx.x;
    const float* xr = x + (size_t)t * HIDDEN;
    float acc[NEXP];
#pragma unroll
    for (int e = 0; e < NEXP; e++) acc[e] = 0.f;
    for (int j = 0; j < HIDDEN / 64; j++) {
        float xv = xr[lane + 64 * j];
#pragma unroll
        for (int e = 0; e < NEXP; e++)
            acc[e] = fmaf(xv, gw[e * HIDDEN + lane + 64 * j], acc[e]);
    }
#pragma unroll
    for (int e = 0; e < NEXP; e++) {
        float v = acc[e];
        for (int off = 32; off > 0; off >>= 1) v += __shfl_xor(v, off, 64);
        acc[e] = v;
    }
    if (lane == 0) {
        float mx = acc[0];
        for (int e = 1; e < NEXP; e++) mx = fmaxf(mx, acc[e]);
        float s[NEXP];
        float sum = 0.f;
        for (int e = 0; e < NEXP; e++) { s[e] = __expf(acc[e] - mx); sum += s[e]; }
        float inv = 1.0f / sum;
        for (int e = 0; e < NEXP; e++) s[e] *= inv;
        int e0 = 0;
        for (int e = 1; e < NEXP; e++) if (s[e] > s[e0]) e0 = e;
        int e1 = -1;
        for (int e = 0; e < NEXP; e++) {
            if (e == e0) continue;
            if (e1 < 0 || s[e] > s[e1]) e1 = e;
        }
        float w0 = s[e0], w1 = s[e1];
        float denom = w0 + w1 + 1e-20f;
        top_i[t * 2 + 0] = e0;
        top_i[t * 2 + 1] = e1;
        top_w[t * 2 + 0] = w0 / denom;
        top_w[t * 2 + 1] = w1 / denom;
    }
}

// ---------------- routing bookkeeping ----------------
__global__ void assign_kernel(const int* __restrict__ top_i, int* __restrict__ cnt,
                              int* __restrict__ rnk) {
    int j = blockIdx.x * blockDim.x + threadIdx.x;
    if (j < NROWS) rnk[j] = atomicAdd(&cnt[top_i[j]], 1);
}

// builds offsets AND the dense (panel, m-block) task table
__global__ void scan_kernel(const int* __restrict__ cnt, int* __restrict__ offs2,
                            int* __restrict__ cnt2, int* __restrict__ task_pm) {
    if (threadIdx.x == 0) {
        int o = 0;
        for (int e = 0; e < NEXP; e++) { offs2[e] = o; cnt2[e] = cnt[e]; o += cnt[e]; }
        offs2[8] = NROWS;          cnt2[8] = NTOK;
        offs2[9] = NROWS + NTOK;   cnt2[9] = NTOK;
        offs2[10] = TROWS;
        int t = 0;
        for (int e = 0; e < NPANEL; e++)
            for (int m0 = 0; m0 < cnt2[e]; m0 += 128)
                task_pm[t++] = (e << 16) | (m0 >> 7);
        for (; t < MAXT; t++) task_pm[t] = -1;
    }
}

__global__ void fill_kernel(const int* __restrict__ top_i, const float* __restrict__ top_w,
                            const int* __restrict__ rnk, const int* __restrict__ offs2,
                            int* __restrict__ tok_of_row, float* __restrict__ w_of_row,
                            int* __restrict__ inv_row) {
    int j = blockIdx.x * blockDim.x + threadIdx.x;
    if (j < NROWS) {
        int row = offs2[top_i[j]] + rnk[j];
        tok_of_row[row] = j;  // token = j>>1
        w_of_row[row] = top_w[j];
        inv_row[j] = row;
    }
}

__global__ void fill_shared(int* __restrict__ tok_of_row) {
    int j = blockIdx.x * blockDim.x + threadIdx.x;  // 0..8191
    tok_of_row[NROWS + j] = (j & (NTOK - 1)) << 1;  // token = j mod 4096
}

// ============ GEMM 1: act = silu(x@Wg)*(x@Wu)  (383.7-us build, verbatim) ==
__global__ __launch_bounds__(256, 2) void gemm_gu(
    const ushort_t* __restrict__ xb, const ushort_t* __restrict__ WgT,
    const ushort_t* __restrict__ WuT, ushort_t* __restrict__ act,
    const int* __restrict__ tok_of_row, const int* __restrict__ offs2,
    const int* __restrict__ cnt2, const int* __restrict__ task_pm) {
    int T = gridDim.x;  // MAXT * (INTER/128), divisible by 8
    int orig = blockIdx.x;
    int logical = (orig & 7) * (T >> 3) + (orig >> 3);
    int task = logical % MAXT;
    int nidx = logical / MAXT;
    int tk = task_pm[task];
    if (tk < 0) return;
    int e = tk >> 16;
    int m0 = (tk & 0xffff) << 7;
    int mcnt = cnt2[e];
    int base = offs2[e];
    int n0 = nidx * 128;
    const ushort_t* Bg = WgT + (size_t)e * INTER * HIDDEN;
    const ushort_t* Bu = WuT + (size_t)e * INTER * HIDDEN;

    __shared__ short As[2 * 8 * 512];
    __shared__ short Bgs[2 * 8 * 512];
    __shared__ short Bus[2 * 8 * 512];

    int tid = threadIdx.x;
    int wave = tid >> 6, lane = tid & 63;
    int wr = wave >> 1, wc = wave & 1;
    int lr = lane & 15;
    int kq = (lane >> 4) * 8;

    int r0 = m0 + 32 * wave + lr, r1 = r0 + 16;
    int rr0 = base + imin(r0, mcnt - 1);
    int rr1 = base + imin(r1, mcnt - 1);
    const ushort_t* srcA0 = xb + (size_t)(tok_of_row[rr0] >> 1) * HIDDEN + kq;
    const ushort_t* srcA1 = xb + (size_t)(tok_of_row[rr1] >> 1) * HIDDEN + kq;
    const ushort_t* srcBg0 = Bg + (size_t)(n0 + 32 * wave + lr) * HIDDEN + kq;
    const ushort_t* srcBg1 = srcBg0 + (size_t)16 * HIDDEN;
    const ushort_t* srcBu0 = Bu + (size_t)(n0 + 32 * wave + lr) * HIDDEN + kq;
    const ushort_t* srcBu1 = srcBu0 + (size_t)16 * HIDDEN;

    f32x4 accG[4][4] = {};
    f32x4 accU[4][4] = {};

#define STAGE_GU(bo, k0)                                                     \
    do {                                                                     \
        GLDS16(srcA0 + (k0), &As[(bo) + (2 * wave) * 512]);                  \
        GLDS16(srcA1 + (k0), &As[(bo) + (2 * wave + 1) * 512]);              \
        GLDS16(srcBg0 + (k0), &Bgs[(bo) + (2 * wave) * 512]);                \
        GLDS16(srcBg1 + (k0), &Bgs[(bo) + (2 * wave + 1) * 512]);            \
        GLDS16(srcBu0 + (k0), &Bus[(bo) + (2 * wave) * 512]);                \
        GLDS16(srcBu1 + (k0), &Bus[(bo) + (2 * wave + 1) * 512]);            \
    } while (0)

    STAGE_GU(0, 0);
    STAGE_GU(4096, 32);

    const int NT = HIDDEN / 32;  // 32
    for (int t = 0; t < NT; t++) {
        int bo = (t & 1) << 12;
        if (t < NT - 1) asm volatile("s_waitcnt vmcnt(6)" ::: "memory");
        else            asm volatile("s_waitcnt vmcnt(0)" ::: "memory");
        __builtin_amdgcn_sched_barrier(0);
        __builtin_amdgcn_s_barrier();
        short8 a[4], bg[4], bu[4];
#pragma unroll
        for (int mi = 0; mi < 4; mi++)
            a[mi] = *reinterpret_cast<const short8*>(
                &As[bo + (wr * 4 + mi) * 512 + lane * 8]);
#pragma unroll
        for (int ni = 0; ni < 4; ni++) {
            bg[ni] = *reinterpret_cast<const short8*>(
                &Bgs[bo + (wc * 4 + ni) * 512 + lane * 8]);
            bu[ni] = *reinterpret_cast<const short8*>(
                &Bus[bo + (wc * 4 + ni) * 512 + lane * 8]);
        }
        asm volatile("s_waitcnt lgkmcnt(0)" ::: "memory");
        __builtin_amdgcn_sched_barrier(0);
        __builtin_amdgcn_s_barrier();
        if (t + 2 < NT) STAGE_GU(bo, (t + 2) * 32);
        __builtin_amdgcn_s_setprio(1);
#pragma unroll
        for (int mi = 0; mi < 4; mi++)
#pragma unroll
            for (int ni = 0; ni < 4; ni++) {
                accG[mi][ni] = __builtin_amdgcn_mfma_f32_16x16x32_bf16(
                    a[mi], bg[ni], accG[mi][ni], 0, 0, 0);
                accU[mi][ni] = __builtin_amdgcn_mfma_f32_16x16x32_bf16(
                    a[mi], bu[ni], accU[mi][ni], 0, 0, 0);
            }
        __builtin_amdgcn_s_setprio(0);
    }
#undef STAGE_GU

#pragma unroll
    for (int mi = 0; mi < 4; mi++) {
#pragma unroll
        for (int r = 0; r < 4; r++) {
            int gm = m0 + wr * 64 + mi * 16 + (lane >> 4) * 4 + r;
            if (gm < mcnt) {
#pragma unroll
                for (int ni = 0; ni < 4; ni++) {
                    int col = n0 + wc * 64 + ni * 16 + lr;
                    float g = accG[mi][ni][r], u = accU[mi][ni][r];
                    act[(size_t)(base + gm) * INTER + col] = f2bf(silu_f(g) * u);
                }
            }
        }
    }
}

// ============ GEMM 2: part = act @ Wd (383.7-us build, verbatim) ===========
__global__ __launch_bounds__(256, 2) void gemm_down(
    const ushort_t* __restrict__ act, const ushort_t* __restrict__ WdT,
    ushort_t* __restrict__ part, const int* __restrict__ offs2,
    const int* __restrict__ cnt2, const int* __restrict__ task_pm) {
    int T = gridDim.x;  // MAXT * (HIDDEN/256)
    int orig = blockIdx.x;
    int logical = (orig & 7) * (T >> 3) + (orig >> 3);
    int task = logical % MAXT;
    int nidx = logical / MAXT;
    int tk = task_pm[task];
    if (tk < 0) return;
    int e = tk >> 16;
    int m0 = (tk & 0xffff) << 7;
    int mcnt = cnt2[e];
    int base = offs2[e];
    int n0 = nidx * 256;
    const ushort_t* Bd = WdT + (size_t)e * HIDDEN * INTER;

    __shared__ short As[2 * 8 * 512];
    __shared__ short Bs[2 * 16 * 512];

    int tid = threadIdx.x;
    int wave = tid >> 6, lane = tid & 63;
    int wr = wave >> 1, wc = wave & 1;
    int lr = lane & 15;
    int kq = (lane >> 4) * 8;

    const ushort_t* srcA0 = act + (size_t)(base + m0 + 32 * wave + lr) * INTER + kq;
    const ushort_t* srcA1 = srcA0 + (size_t)16 * INTER;
    const ushort_t* srcB0 = Bd + (size_t)(n0 + 64 * wave + lr) * INTER + kq;
    const ushort_t* srcB1 = srcB0 + (size_t)16 * INTER;
    const ushort_t* srcB2 = srcB0 + (size_t)32 * INTER;
    const ushort_t* srcB3 = srcB0 + (size_t)48 * INTER;

    f32x4 acc[4][8] = {};

#define STAGE_D(boA, boB, k0)                                                \
    do {                                                                     \
        GLDS16(srcA0 + (k0), &As[(boA) + (2 * wave) * 512]);                 \
        GLDS16(srcA1 + (k0), &As[(boA) + (2 * wave + 1) * 512]);             \
        GLDS16(srcB0 + (k0), &Bs[(boB) + (4 * wave) * 512]);                 \
        GLDS16(srcB1 + (k0), &Bs[(boB) + (4 * wave + 1) * 512]);             \
        GLDS16(srcB2 + (k0), &Bs[(boB) + (4 * wave + 2) * 512]);             \
        GLDS16(srcB3 + (k0), &Bs[(boB) + (4 * wave + 3) * 512]);             \
    } while (0)

    STAGE_D(0, 0, 0);
    STAGE_D(4096, 8192, 32);

    const int NT = INTER / 32;  // 44
    for (int t = 0; t < NT; t++) {
        int boA = (t & 1) << 12;
        int boB = (t & 1) << 13;
        if (t < NT - 1) asm volatile("s_waitcnt vmcnt(6)" ::: "memory");
        else            asm volatile("s_waitcnt vmcnt(0)" ::: "memory");
        __builtin_amdgcn_sched_barrier(0);
        __builtin_amdgcn_s_barrier();
        short8 a[4], b[8];
#pragma unroll
        for (int mi = 0; mi < 4; mi++)
            a[mi] = *reinterpret_cast<const short8*>(
                &As[boA + (wr * 4 + mi) * 512 + lane * 8]);
#pragma unroll
        for (int ni = 0; ni < 8; ni++)
            b[ni] = *reinterpret_cast<const short8*>(
                &Bs[boB + (wc * 8 + ni) * 512 + lane * 8]);
        asm volatile("s_waitcnt lgkmcnt(0)" ::: "memory");
        __builtin_amdgcn_sched_barrier(0);
        __builtin_amdgcn_s_barrier();
        if (t + 2 < NT) STAGE_D(boA, boB, (t + 2) * 32);
        __builtin_amdgcn_s_setprio(1);
#pragma unroll
        for (int mi = 0; mi < 4; mi++)
#pragma unroll
            for (int ni = 0; ni < 8; ni++)
                acc[mi][ni] = __builtin_amdgcn_mfma_f32_16x16x32_bf16(
                    a[mi], b[ni], acc[mi][ni], 0, 0, 0);
        __builtin_amdgcn_s_setprio(0);
    }
#undef STAGE_D

#pragma unroll
    for (int mi = 0; mi < 4; mi++) {
#pragma unroll
        for (int r = 0; r < 4; r++) {
            int gm = m0 + wr * 64 + mi * 16 + (lane >> 4) * 4 + r;
            if (gm < mcnt) {
#pragma unroll
                for (int ni = 0; ni < 8; ni++) {
                    int col = n0 + wc * 128 + ni * 16 + lr;
                    part[(size_t)(base + gm) * HIDDEN + col] = f2bf(acc[mi][ni][r]);
                }
            }
        }
    }
}

// ============ combine: out[t] = w0*part[r0] + w1*part[r1] + part[s8] + part[s9]
__global__ __launch_bounds__(256) void combine_kernel(
    const ushort_t* __restrict__ part, const int* __restrict__ inv_row,
    const float* __restrict__ w_of_row, float* __restrict__ out) {
    int t = blockIdx.x;
    int c = threadIdx.x * 4;
    int r0 = inv_row[2 * t], r1 = inv_row[2 * t + 1];
    float w0 = w_of_row[r0], w1 = w_of_row[r1];
    ushort4 a0 = *reinterpret_cast<const ushort4*>(&part[(size_t)r0 * HIDDEN + c]);
    ushort4 a1 = *reinterpret_cast<const ushort4*>(&part[(size_t)r1 * HIDDEN + c]);
    ushort4 a2 = *reinterpret_cast<const ushort4*>(&part[((size_t)NROWS + t) * HIDDEN + c]);
    ushort4 a3 = *reinterpret_cast<const ushort4*>(&part[((size_t)NROWS + NTOK + t) * HIDDEN + c]);
    float4 o;
    o.x = w0 * bf2f(a0.x) + w1 * bf2f(a1.x) + bf2f(a2.x) + bf2f(a3.x);
    o.y = w0 * bf2f(a0.y) + w1 * bf2f(a1.y) + bf2f(a2.y) + bf2f(a3.y);
    o.z = w0 * bf2f(a0.z) + w1 * bf2f(a1.z) + bf2f(a2.z) + bf2f(a3.z);
    o.w = w0 * bf2f(a0.w) + w1 * bf2f(a1.w) + bf2f(a2.w) + bf2f(a3.w);
    *reinterpret_cast<float4*>(&out[(size_t)t * HIDDEN + c]) = o;
}

extern "C" void kernel_launch(void* const* d_in, const int* in_sizes, int n_in,
                              void* d_out, int out_size, void* d_ws, size_t ws_size,
                              hipStream_t stream) {
    const float* x   = (const float*)d_in[0];
    const float* gw  = (const float*)d_in[1];
    const float* wg  = (const float*)d_in[2];
    const float* wu  = (const float*)d_in[3];
    const float* wd  = (const float*)d_in[4];
    const float* swg = (const float*)d_in[5];
    const float* swu = (const float*)d_in[6];
    const float* swd = (const float*)d_in[7];
    float* out = (float*)d_out;

    // ---- workspace layout (bf16 buffers first, 16B-aligned) ----
    const size_t XB   = (size_t)NTOK * HIDDEN;
    const size_t WPAN = (size_t)NPANEL * INTER * HIDDEN;
    const size_t ACT  = (size_t)TROWS * INTER;
    const size_t PART = (size_t)TROWS * HIDDEN;
    ushort_t* xb   = (ushort_t*)d_ws;
    ushort_t* wgT  = xb + XB;
    ushort_t* wuT  = wgT + WPAN;
    ushort_t* wdT  = wuT + WPAN;
    ushort_t* act  = wdT + WPAN;
    ushort_t* part = act + ACT;
    int* ib = (int*)(part + PART);
    int* top_i      = ib;                 // NROWS
    int* rnk        = ib + NROWS;         // NROWS
    int* cnt        = ib + 2 * NROWS;     // 8
    int* offs2      = ib + 2 * NROWS + 8; // 16
    int* cnt2       = offs2 + 16;         // 16
    int* task_pm    = cnt2 + 16;          // MAXT
    int* tok_of_row = task_pm + MAXT;     // TROWS
    int* inv_row    = tok_of_row + TROWS; // NROWS
    float* top_w    = (float*)(inv_row + NROWS);  // NROWS
    float* w_of_row = top_w + NROWS;              // TROWS

    // ---- 1. dtype conversions (wide-tile transposes) ----
    conv_x<<<(NTOK * HIDDEN) / (256 * 4), 256, 0, stream>>>(x, xb);
    tconv_wide<<<dim3(INTER / 32, HIDDEN / 512, NEXP), 256, 0, stream>>>(
        wg, wgT, HIDDEN, INTER, (long)HIDDEN * INTER, (long)INTER * HIDDEN, 512);
    tconv_wide<<<dim3(INTER / 32, HIDDEN / 512, NEXP), 256, 0, stream>>>(
        wu, wuT, HIDDEN, INTER, (long)HIDDEN * INTER, (long)INTER * HIDDEN, 512);
    tconv_wide<<<dim3(SINTER / 32, HIDDEN / 512, 1), 256, 0, stream>>>(
        swg, wgT + (size_t)8 * INTER * HIDDEN, HIDDEN, SINTER, 0, 0, 512);
    tconv_wide<<<dim3(SINTER / 32, HIDDEN / 512, 1), 256, 0, stream>>>(
        swu, wuT + (size_t)8 * INTER * HIDDEN, HIDDEN, SINTER, 0, 0, 512);
    tconv_wide<<<dim3(HIDDEN / 32, INTER / 704, NEXP), 256, 0, stream>>>(
        wd, wdT, INTER, HIDDEN, (long)INTER * HIDDEN, (long)HIDDEN * INTER, 704);
    tconv_wide<<<dim3(HIDDEN / 32, INTER / 704, 2), 256, 0, stream>>>(
        swd, wdT + (size_t)8 * HIDDEN * INTER, INTER, HIDDEN,
        (long)INTER * HIDDEN, (long)HIDDEN * INTER, 704);

    // ---- 2. gate + routing ----
    gate_kernel<<<NTOK, 64, 0, stream>>>(x, gw, top_i, top_w);
    hipMemsetAsync(cnt, 0, 8 * sizeof(int), stream);
    assign_kernel<<<NROWS / 256, 256, 0, stream>>>(top_i, cnt, rnk);
    scan_kernel<<<1, 1, 0, stream>>>(cnt, offs2, cnt2, task_pm);
    fill_kernel<<<NROWS / 256, 256, 0, stream>>>(top_i, top_w, rnk, offs2,
                                                 tok_of_row, w_of_row, inv_row);
    fill_shared<<<NROWS / 256, 256, 0, stream>>>(tok_of_row);

    // ---- 3. grouped SwiGLU GEMMs (dense 1-D swizzled grids) ----
    gemm_gu<<<MAXT * (INTER / 128), 256, 0, stream>>>(
        xb, wgT, wuT, act, tok_of_row, offs2, cnt2, task_pm);
    gemm_down<<<MAXT * (HIDDEN / 256), 256, 0, stream>>>(
        act, wdT, part, offs2, cnt2, task_pm);
    combine_kernel<<<NTOK, 256, 0, stream>>>(part, inv_row, w_of_row, out);
}

// Round 19
// 383.646 us; speedup vs baseline: 1.1239x; 1.0303x over previous
//
#include <hip/hip_runtime.h>
#include <hip/hip_bf16.h>
#include <math.h>

#define HIDDEN 1024
#define NEXP 8
#define TOPK 2
#define INTER 1408
#define SINTER 2816
#define NTOK 4096
#define NROWS (NTOK * TOPK) /* 8192 routed rows */
#define NPANEL 10           /* 8 routed + 2 shared halves */
#define TROWS 16384         /* NROWS + 2*NTOK */
#define MAXT 136            /* max (panel, m-block) tasks */

typedef unsigned short ushort_t;
typedef __attribute__((ext_vector_type(8))) short short8;
typedef __attribute__((ext_vector_type(4))) float f32x4;

__device__ __forceinline__ ushort_t f2bf(float f) {
    unsigned int b = __float_as_uint(f);
    unsigned int r = (b + 0x7FFFu + ((b >> 16) & 1u)) >> 16;
    return (ushort_t)r;
}
__device__ __forceinline__ float bf2f(ushort_t u) {
    return __uint_as_float(((unsigned int)u) << 16);
}
__device__ __forceinline__ float silu_f(float g) {
    return g * (1.0f / (1.0f + __expf(-g)));
}
__device__ __forceinline__ int imin(int a, int b) { return a < b ? a : b; }

#define GLDS16(gp, lp) __builtin_amdgcn_global_load_lds(                     \
    (const __attribute__((address_space(1))) void*)(gp),                     \
    (__attribute__((address_space(3))) void*)(lp), 16, 0, 0)

// ---------------- fp32 -> bf16 elementwise (x) ----------------
__global__ void conv_x(const float* __restrict__ src, ushort_t* __restrict__ dst) {
    int i = (blockIdx.x * 256 + threadIdx.x) * 4;
    float4 v = *reinterpret_cast<const float4*>(&src[i]);
    union { ushort_t h[4]; unsigned long long ll; } p;
    p.h[0] = f2bf(v.x); p.h[1] = f2bf(v.y); p.h[2] = f2bf(v.z); p.h[3] = f2bf(v.w);
    *reinterpret_cast<unsigned long long*>(&dst[i]) = p.ll;
}

// ---- fp32 [R][C] -> bf16 [C][R] transpose-convert -------------------------
__global__ void tconv(const float* __restrict__ src, ushort_t* __restrict__ dst,
                      int R, int C, long sstride, long dstride) {
    src += (size_t)blockIdx.z * sstride;
    dst += (size_t)blockIdx.z * dstride;
    __shared__ float tile[32][33];
    int ct = blockIdx.x * 32, rt = blockIdx.y * 32;
    int tx = threadIdx.x, ty = threadIdx.y;  // 32 x 8
#pragma unroll
    for (int i = 0; i < 4; i++)
        tile[ty + 8 * i][tx] = src[(size_t)(rt + ty + 8 * i) * C + ct + tx];
    __syncthreads();
#pragma unroll
    for (int i = 0; i < 4; i++)
        dst[(size_t)(ct + ty + 8 * i) * R + rt + tx] = f2bf(tile[tx][ty + 8 * i]);
}

// ---------------- gate: logits -> softmax -> top2 -> normalized weights ----
__global__ void gate_kernel(const float* __restrict__ x, const float* __restrict__ gw,
                            int* __restrict__ top_i, float* __restrict__ top_w) {
    int t = blockIdx.x;
    int lane = threadIdx.x;
    const float* xr = x + (size_t)t * HIDDEN;
    float acc[NEXP];
#pragma unroll
    for (int e = 0; e < NEXP; e++) acc[e] = 0.f;
    for (int j = 0; j < HIDDEN / 64; j++) {
        float xv = xr[lane + 64 * j];
#pragma unroll
        for (int e = 0; e < NEXP; e++)
            acc[e] = fmaf(xv, gw[e * HIDDEN + lane + 64 * j], acc[e]);
    }
#pragma unroll
    for (int e = 0; e < NEXP; e++) {
        float v = acc[e];
        for (int off = 32; off > 0; off >>= 1) v += __shfl_xor(v, off, 64);
        acc[e] = v;
    }
    if (lane == 0) {
        float mx = acc[0];
        for (int e = 1; e < NEXP; e++) mx = fmaxf(mx, acc[e]);
        float s[NEXP];
        float sum = 0.f;
        for (int e = 0; e < NEXP; e++) { s[e] = __expf(acc[e] - mx); sum += s[e]; }
        float inv = 1.0f / sum;
        for (int e = 0; e < NEXP; e++) s[e] *= inv;
        int e0 = 0;
        for (int e = 1; e < NEXP; e++) if (s[e] > s[e0]) e0 = e;
        int e1 = -1;
        for (int e = 0; e < NEXP; e++) {
            if (e == e0) continue;
            if (e1 < 0 || s[e] > s[e1]) e1 = e;
        }
        float w0 = s[e0], w1 = s[e1];
        float denom = w0 + w1 + 1e-20f;
        top_i[t * 2 + 0] = e0;
        top_i[t * 2 + 1] = e1;
        top_w[t * 2 + 0] = w0 / denom;
        top_w[t * 2 + 1] = w1 / denom;
    }
}

// ---------------- routing bookkeeping ----------------
__global__ void assign_kernel(const int* __restrict__ top_i, int* __restrict__ cnt,
                              int* __restrict__ rnk) {
    int j = blockIdx.x * blockDim.x + threadIdx.x;
    if (j < NROWS) rnk[j] = atomicAdd(&cnt[top_i[j]], 1);
}

// builds offsets AND the dense (panel, m-block) task table
__global__ void scan_kernel(const int* __restrict__ cnt, int* __restrict__ offs2,
                            int* __restrict__ cnt2, int* __restrict__ task_pm) {
    if (threadIdx.x == 0) {
        int o = 0;
        for (int e = 0; e < NEXP; e++) { offs2[e] = o; cnt2[e] = cnt[e]; o += cnt[e]; }
        offs2[8] = NROWS;          cnt2[8] = NTOK;
        offs2[9] = NROWS + NTOK;   cnt2[9] = NTOK;
        offs2[10] = TROWS;
        int t = 0;
        for (int e = 0; e < NPANEL; e++)
            for (int m0 = 0; m0 < cnt2[e]; m0 += 128)
                task_pm[t++] = (e << 16) | (m0 >> 7);
        for (; t < MAXT; t++) task_pm[t] = -1;
    }
}

__global__ void fill_kernel(const int* __restrict__ top_i, const float* __restrict__ top_w,
                            const int* __restrict__ rnk, const int* __restrict__ offs2,
                            int* __restrict__ tok_of_row, float* __restrict__ w_of_row,
                            int* __restrict__ inv_row) {
    int j = blockIdx.x * blockDim.x + threadIdx.x;
    if (j < NROWS) {
        int row = offs2[top_i[j]] + rnk[j];
        tok_of_row[row] = j;  // token = j>>1
        w_of_row[row] = top_w[j];
        inv_row[j] = row;
    }
}

__global__ void fill_shared(int* __restrict__ tok_of_row) {
    int j = blockIdx.x * blockDim.x + threadIdx.x;  // 0..8191
    tok_of_row[NROWS + j] = (j & (NTOK - 1)) << 1;  // token = j mod 4096
}

// ============ GEMM 1: act = silu(x@Wg)*(x@Wu) ==============================
// 256 thr / 4 waves (2x2), tile 128Mx128N over BOTH Wg and Wu (32 MFMA per
// window), BK=32, fragment-ordered LDS, DOUBLE-buffered (48KB) with
// T4 counted-vmcnt prefetch: stage tile t+2 after reads of tile t; top of
// step waits vmcnt(6) so next tile's loads stay in flight.
__global__ __launch_bounds__(256, 2) void gemm_gu(
    const ushort_t* __restrict__ xb, const ushort_t* __restrict__ WgT,
    const ushort_t* __restrict__ WuT, ushort_t* __restrict__ act,
    const int* __restrict__ tok_of_row, const int* __restrict__ offs2,
    const int* __restrict__ cnt2, const int* __restrict__ task_pm) {
    int T = gridDim.x;  // MAXT * (INTER/128), divisible by 8
    int orig = blockIdx.x;
    int logical = (orig & 7) * (T >> 3) + (orig >> 3);
    int task = logical % MAXT;
    int nidx = logical / MAXT;
    int tk = task_pm[task];
    if (tk < 0) return;
    int e = tk >> 16;
    int m0 = (tk & 0xffff) << 7;
    int mcnt = cnt2[e];
    int base = offs2[e];
    int n0 = nidx * 128;
    const ushort_t* Bg = WgT + (size_t)e * INTER * HIDDEN;
    const ushort_t* Bu = WuT + (size_t)e * INTER * HIDDEN;

    __shared__ short As[2 * 8 * 512];
    __shared__ short Bgs[2 * 8 * 512];
    __shared__ short Bus[2 * 8 * 512];

    int tid = threadIdx.x;
    int wave = tid >> 6, lane = tid & 63;
    int wr = wave >> 1, wc = wave & 1;  // 2x2 waves, each 64x64
    int lr = lane & 15;
    int kq = (lane >> 4) * 8;  // k-chunk of this lane (8 bf16 = 16B)

    int r0 = m0 + 32 * wave + lr, r1 = r0 + 16;
    int rr0 = base + imin(r0, mcnt - 1);
    int rr1 = base + imin(r1, mcnt - 1);
    const ushort_t* srcA0 = xb + (size_t)(tok_of_row[rr0] >> 1) * HIDDEN + kq;
    const ushort_t* srcA1 = xb + (size_t)(tok_of_row[rr1] >> 1) * HIDDEN + kq;
    const ushort_t* srcBg0 = Bg + (size_t)(n0 + 32 * wave + lr) * HIDDEN + kq;
    const ushort_t* srcBg1 = srcBg0 + (size_t)16 * HIDDEN;
    const ushort_t* srcBu0 = Bu + (size_t)(n0 + 32 * wave + lr) * HIDDEN + kq;
    const ushort_t* srcBu1 = srcBu0 + (size_t)16 * HIDDEN;

    f32x4 accG[4][4] = {};
    f32x4 accU[4][4] = {};

#define STAGE_GU(bo, k0)                                                     \
    do {                                                                     \
        GLDS16(srcA0 + (k0), &As[(bo) + (2 * wave) * 512]);                  \
        GLDS16(srcA1 + (k0), &As[(bo) + (2 * wave + 1) * 512]);              \
        GLDS16(srcBg0 + (k0), &Bgs[(bo) + (2 * wave) * 512]);                \
        GLDS16(srcBg1 + (k0), &Bgs[(bo) + (2 * wave + 1) * 512]);            \
        GLDS16(srcBu0 + (k0), &Bus[(bo) + (2 * wave) * 512]);                \
        GLDS16(srcBu1 + (k0), &Bus[(bo) + (2 * wave + 1) * 512]);            \
    } while (0)

    STAGE_GU(0, 0);
    STAGE_GU(4096, 32);

    const int NT = HIDDEN / 32;  // 32
    for (int t = 0; t < NT; t++) {
        int bo = (t & 1) << 12;  // *4096 elements
        if (t < NT - 1) asm volatile("s_waitcnt vmcnt(6)" ::: "memory");
        else            asm volatile("s_waitcnt vmcnt(0)" ::: "memory");
        __builtin_amdgcn_sched_barrier(0);
        __builtin_amdgcn_s_barrier();  // buf[t&1] ready for all waves
        short8 a[4], bg[4], bu[4];
#pragma unroll
        for (int mi = 0; mi < 4; mi++)
            a[mi] = *reinterpret_cast<const short8*>(
                &As[bo + (wr * 4 + mi) * 512 + lane * 8]);
#pragma unroll
        for (int ni = 0; ni < 4; ni++) {
            bg[ni] = *reinterpret_cast<const short8*>(
                &Bgs[bo + (wc * 4 + ni) * 512 + lane * 8]);
            bu[ni] = *reinterpret_cast<const short8*>(
                &Bus[bo + (wc * 4 + ni) * 512 + lane * 8]);
        }
        asm volatile("s_waitcnt lgkmcnt(0)" ::: "memory");
        __builtin_amdgcn_sched_barrier(0);
        __builtin_amdgcn_s_barrier();  // all reads of buf[t&1] done
        if (t + 2 < NT) STAGE_GU(bo, (t + 2) * 32);
        __builtin_amdgcn_s_setprio(1);
#pragma unroll
        for (int mi = 0; mi < 4; mi++)
#pragma unroll
            for (int ni = 0; ni < 4; ni++) {
                accG[mi][ni] = __builtin_amdgcn_mfma_f32_16x16x32_bf16(
                    a[mi], bg[ni], accG[mi][ni], 0, 0, 0);
                accU[mi][ni] = __builtin_amdgcn_mfma_f32_16x16x32_bf16(
                    a[mi], bu[ni], accU[mi][ni], 0, 0, 0);
            }
        __builtin_amdgcn_s_setprio(0);
    }
#undef STAGE_GU

    // epilogue: silu(g)*u -> bf16 act (compact rows)
#pragma unroll
    for (int mi = 0; mi < 4; mi++) {
#pragma unroll
        for (int r = 0; r < 4; r++) {
            int gm = m0 + wr * 64 + mi * 16 + (lane >> 4) * 4 + r;
            if (gm < mcnt) {
#pragma unroll
                for (int ni = 0; ni < 4; ni++) {
                    int col = n0 + wc * 64 + ni * 16 + lr;
                    float g = accG[mi][ni][r], u = accU[mi][ni][r];
                    act[(size_t)(base + gm) * INTER + col] = f2bf(silu_f(g) * u);
                }
            }
        }
    }
}

// ============ GEMM 2: part = act @ Wd (compact rows, plain bf16 stores) ====
// Tile 128Mx256N (32 MFMA/window), BK=32, double-buffered 48KB LDS, same
// counted-vmcnt prefetch pipeline. NO atomics.
__global__ __launch_bounds__(256, 2) void gemm_down(
    const ushort_t* __restrict__ act, const ushort_t* __restrict__ WdT,
    ushort_t* __restrict__ part, const int* __restrict__ offs2,
    const int* __restrict__ cnt2, const int* __restrict__ task_pm) {
    int T = gridDim.x;  // MAXT * (HIDDEN/256)
    int orig = blockIdx.x;
    int logical = (orig & 7) * (T >> 3) + (orig >> 3);
    int task = logical % MAXT;
    int nidx = logical / MAXT;
    int tk = task_pm[task];
    if (tk < 0) return;
    int e = tk >> 16;
    int m0 = (tk & 0xffff) << 7;
    int mcnt = cnt2[e];
    int base = offs2[e];
    int n0 = nidx * 256;
    const ushort_t* Bd = WdT + (size_t)e * HIDDEN * INTER;

    __shared__ short As[2 * 8 * 512];
    __shared__ short Bs[2 * 16 * 512];

    int tid = threadIdx.x;
    int wave = tid >> 6, lane = tid & 63;
    int wr = wave >> 1, wc = wave & 1;  // each wave: 64M x 128N
    int lr = lane & 15;
    int kq = (lane >> 4) * 8;

    const ushort_t* srcA0 = act + (size_t)(base + m0 + 32 * wave + lr) * INTER + kq;
    const ushort_t* srcA1 = srcA0 + (size_t)16 * INTER;
    const ushort_t* srcB0 = Bd + (size_t)(n0 + 64 * wave + lr) * INTER + kq;
    const ushort_t* srcB1 = srcB0 + (size_t)16 * INTER;
    const ushort_t* srcB2 = srcB0 + (size_t)32 * INTER;
    const ushort_t* srcB3 = srcB0 + (size_t)48 * INTER;

    f32x4 acc[4][8] = {};

#define STAGE_D(boA, boB, k0)                                                \
    do {                                                                     \
        GLDS16(srcA0 + (k0), &As[(boA) + (2 * wave) * 512]);                 \
        GLDS16(srcA1 + (k0), &As[(boA) + (2 * wave + 1) * 512]);             \
        GLDS16(srcB0 + (k0), &Bs[(boB) + (4 * wave) * 512]);                 \
        GLDS16(srcB1 + (k0), &Bs[(boB) + (4 * wave + 1) * 512]);             \
        GLDS16(srcB2 + (k0), &Bs[(boB) + (4 * wave + 2) * 512]);             \
        GLDS16(srcB3 + (k0), &Bs[(boB) + (4 * wave + 3) * 512]);             \
    } while (0)

    STAGE_D(0, 0, 0);
    STAGE_D(4096, 8192, 32);

    const int NT = INTER / 32;  // 44
    for (int t = 0; t < NT; t++) {
        int boA = (t & 1) << 12;  // *4096
        int boB = (t & 1) << 13;  // *8192
        if (t < NT - 1) asm volatile("s_waitcnt vmcnt(6)" ::: "memory");
        else            asm volatile("s_waitcnt vmcnt(0)" ::: "memory");
        __builtin_amdgcn_sched_barrier(0);
        __builtin_amdgcn_s_barrier();
        short8 a[4], b[8];
#pragma unroll
        for (int mi = 0; mi < 4; mi++)
            a[mi] = *reinterpret_cast<const short8*>(
                &As[boA + (wr * 4 + mi) * 512 + lane * 8]);
#pragma unroll
        for (int ni = 0; ni < 8; ni++)
            b[ni] = *reinterpret_cast<const short8*>(
                &Bs[boB + (wc * 8 + ni) * 512 + lane * 8]);
        asm volatile("s_waitcnt lgkmcnt(0)" ::: "memory");
        __builtin_amdgcn_sched_barrier(0);
        __builtin_amdgcn_s_barrier();
        if (t + 2 < NT) STAGE_D(boA, boB, (t + 2) * 32);
        __builtin_amdgcn_s_setprio(1);
#pragma unroll
        for (int mi = 0; mi < 4; mi++)
#pragma unroll
            for (int ni = 0; ni < 8; ni++)
                acc[mi][ni] = __builtin_amdgcn_mfma_f32_16x16x32_bf16(
                    a[mi], b[ni], acc[mi][ni], 0, 0, 0);
        __builtin_amdgcn_s_setprio(0);
    }
#undef STAGE_D

#pragma unroll
    for (int mi = 0; mi < 4; mi++) {
#pragma unroll
        for (int r = 0; r < 4; r++) {
            int gm = m0 + wr * 64 + mi * 16 + (lane >> 4) * 4 + r;
            if (gm < mcnt) {
#pragma unroll
                for (int ni = 0; ni < 8; ni++) {
                    int col = n0 + wc * 128 + ni * 16 + lr;
                    part[(size_t)(base + gm) * HIDDEN + col] = f2bf(acc[mi][ni][r]);
                }
            }
        }
    }
}

// ============ combine: out[t] = w0*part[r0] + w1*part[r1] + part[s8] + part[s9]
__global__ __launch_bounds__(256) void combine_kernel(
    const ushort_t* __restrict__ part, const int* __restrict__ inv_row,
    const float* __restrict__ w_of_row, float* __restrict__ out) {
    int t = blockIdx.x;
    int c = threadIdx.x * 4;
    int r0 = inv_row[2 * t], r1 = inv_row[2 * t + 1];
    float w0 = w_of_row[r0], w1 = w_of_row[r1];
    ushort4 a0 = *reinterpret_cast<const ushort4*>(&part[(size_t)r0 * HIDDEN + c]);
    ushort4 a1 = *reinterpret_cast<const ushort4*>(&part[(size_t)r1 * HIDDEN + c]);
    ushort4 a2 = *reinterpret_cast<const ushort4*>(&part[((size_t)NROWS + t) * HIDDEN + c]);
    ushort4 a3 = *reinterpret_cast<const ushort4*>(&part[((size_t)NROWS + NTOK + t) * HIDDEN + c]);
    float4 o;
    o.x = w0 * bf2f(a0.x) + w1 * bf2f(a1.x) + bf2f(a2.x) + bf2f(a3.x);
    o.y = w0 * bf2f(a0.y) + w1 * bf2f(a1.y) + bf2f(a2.y) + bf2f(a3.y);
    o.z = w0 * bf2f(a0.z) + w1 * bf2f(a1.z) + bf2f(a2.z) + bf2f(a3.z);
    o.w = w0 * bf2f(a0.w) + w1 * bf2f(a1.w) + bf2f(a2.w) + bf2f(a3.w);
    *reinterpret_cast<float4*>(&out[(size_t)t * HIDDEN + c]) = o;
}

extern "C" void kernel_launch(void* const* d_in, const int* in_sizes, int n_in,
                              void* d_out, int out_size, void* d_ws, size_t ws_size,
                              hipStream_t stream) {
    const float* x   = (const float*)d_in[0];
    const float* gw  = (const float*)d_in[1];
    const float* wg  = (const float*)d_in[2];
    const float* wu  = (const float*)d_in[3];
    const float* wd  = (const float*)d_in[4];
    const float* swg = (const float*)d_in[5];
    const float* swu = (const float*)d_in[6];
    const float* swd = (const float*)d_in[7];
    float* out = (float*)d_out;

    // ---- workspace layout (bf16 buffers first, 16B-aligned) ----
    const size_t XB   = (size_t)NTOK * HIDDEN;
    const size_t WPAN = (size_t)NPANEL * INTER * HIDDEN;
    const size_t ACT  = (size_t)TROWS * INTER;
    const size_t PART = (size_t)TROWS * HIDDEN;
    ushort_t* xb   = (ushort_t*)d_ws;
    ushort_t* wgT  = xb + XB;
    ushort_t* wuT  = wgT + WPAN;
    ushort_t* wdT  = wuT + WPAN;
    ushort_t* act  = wdT + WPAN;
    ushort_t* part = act + ACT;
    int* ib = (int*)(part + PART);
    int* top_i      = ib;                 // NROWS
    int* rnk        = ib + NROWS;         // NROWS
    int* cnt        = ib + 2 * NROWS;     // 8
    int* offs2      = ib + 2 * NROWS + 8; // 16
    int* cnt2       = offs2 + 16;         // 16
    int* task_pm    = cnt2 + 16;          // MAXT
    int* tok_of_row = task_pm + MAXT;     // TROWS
    int* inv_row    = tok_of_row + TROWS; // NROWS
    float* top_w    = (float*)(inv_row + NROWS);  // NROWS
    float* w_of_row = top_w + NROWS;              // TROWS

    // ---- 1. dtype conversions (+ weight transposes to [N][K]) ----
    conv_x<<<(NTOK * HIDDEN) / (256 * 4), 256, 0, stream>>>(x, xb);
    dim3 tb(32, 8);
    tconv<<<dim3(INTER / 32, HIDDEN / 32, NEXP), tb, 0, stream>>>(
        wg, wgT, HIDDEN, INTER, (long)HIDDEN * INTER, (long)INTER * HIDDEN);
    tconv<<<dim3(INTER / 32, HIDDEN / 32, NEXP), tb, 0, stream>>>(
        wu, wuT, HIDDEN, INTER, (long)HIDDEN * INTER, (long)INTER * HIDDEN);
    tconv<<<dim3(SINTER / 32, HIDDEN / 32, 1), tb, 0, stream>>>(
        swg, wgT + (size_t)8 * INTER * HIDDEN, HIDDEN, SINTER, 0, 0);
    tconv<<<dim3(SINTER / 32, HIDDEN / 32, 1), tb, 0, stream>>>(
        swu, wuT + (size_t)8 * INTER * HIDDEN, HIDDEN, SINTER, 0, 0);
    tconv<<<dim3(HIDDEN / 32, INTER / 32, NEXP), tb, 0, stream>>>(
        wd, wdT, INTER, HIDDEN, (long)INTER * HIDDEN, (long)HIDDEN * INTER);
    tconv<<<dim3(HIDDEN / 32, INTER / 32, 2), tb, 0, stream>>>(
        swd, wdT + (size_t)8 * HIDDEN * INTER, INTER, HIDDEN,
        (long)INTER * HIDDEN, (long)HIDDEN * INTER);

    // ---- 2. gate + routing ----
    gate_kernel<<<NTOK, 64, 0, stream>>>(x, gw, top_i, top_w);
    hipMemsetAsync(cnt, 0, 8 * sizeof(int), stream);
    assign_kernel<<<NROWS / 256, 256, 0, stream>>>(top_i, cnt, rnk);
    scan_kernel<<<1, 1, 0, stream>>>(cnt, offs2, cnt2, task_pm);
    fill_kernel<<<NROWS / 256, 256, 0, stream>>>(top_i, top_w, rnk, offs2,
                                                 tok_of_row, w_of_row, inv_row);
    fill_shared<<<NROWS / 256, 256, 0, stream>>>(tok_of_row);

    // ---- 3. grouped SwiGLU GEMMs (dense 1-D swizzled grids) ----
    gemm_gu<<<MAXT * (INTER / 128), 256, 0, stream>>>(
        xb, wgT, wuT, act, tok_of_row, offs2, cnt2, task_pm);
    gemm_down<<<MAXT * (HIDDEN / 256), 256, 0, stream>>>(
        act, wdT, part, offs2, cnt2, task_pm);
    combine_kernel<<<NTOK, 256, 0, stream>>>(part, inv_row, w_of_row, out);
}